// Round 1
// baseline (34.842 us; speedup 1.0000x reference)
//
#include <hip/hip_runtime.h>

#define EPS 1e-8f
#define NBLOCKS 2048
#define NTHREADS 256

// Kernel 1: grid-stride partial reduction.
// Each float4 group j covers (b,t) items 2j and 2j+1:
//   outputs[4j..4j+3] = {o[2j,0], o[2j,1], o[2j+1,0], o[2j+1,1]}
//   targets likewise, weights[2j], weights[2j+1].
__global__ __launch_bounds__(NTHREADS) void cl_partial(
    const float4* __restrict__ o4p,
    const float4* __restrict__ t4p,
    const float2* __restrict__ w2p,
    float* __restrict__ ws,
    int M)  // M = number of float4 groups = N/2
{
    int tid = blockIdx.x * blockDim.x + threadIdx.x;
    int stride = gridDim.x * blockDim.x;

    float s0 = 0.0f, s1 = 0.0f;

    for (int j = tid; j < M; j += stride) {
        float4 o4 = o4p[j];
        float4 t4 = t4p[j];
        float2 w2 = w2p[j];

        // item A = 2j : (o4.x, o4.y), targets (t4.x, t4.y), weight w2.x
        float lA0m = __logf((1.0f - o4.x) + EPS);
        float lA0  = __logf(o4.x + EPS);
        float lA1m = __logf((1.0f - o4.y) + EPS);
        float lA1  = __logf(o4.y + EPS);
        s0 += (t4.x * lA0m + t4.y * lA0) * w2.x;
        s1 += (t4.x * lA1m + t4.y * lA1) * w2.x;

        // item B = 2j+1 : (o4.z, o4.w), targets (t4.z, t4.w), weight w2.y
        float lB0m = __logf((1.0f - o4.z) + EPS);
        float lB0  = __logf(o4.z + EPS);
        float lB1m = __logf((1.0f - o4.w) + EPS);
        float lB1  = __logf(o4.w + EPS);
        s0 += (t4.z * lB0m + t4.w * lB0) * w2.y;
        s1 += (t4.z * lB1m + t4.w * lB1) * w2.y;
    }

    // wave (64-lane) reduction
    #pragma unroll
    for (int off = 32; off > 0; off >>= 1) {
        s0 += __shfl_down(s0, off, 64);
        s1 += __shfl_down(s1, off, 64);
    }

    __shared__ float sm[ (NTHREADS/64) * 2 ];
    int wave = threadIdx.x >> 6;
    int lane = threadIdx.x & 63;
    if (lane == 0) { sm[wave * 2 + 0] = s0; sm[wave * 2 + 1] = s1; }
    __syncthreads();

    if (threadIdx.x == 0) {
        float b0 = 0.0f, b1 = 0.0f;
        #pragma unroll
        for (int wv = 0; wv < NTHREADS / 64; ++wv) {
            b0 += sm[wv * 2 + 0];
            b1 += sm[wv * 2 + 1];
        }
        ws[blockIdx.x * 2 + 0] = b0;
        ws[blockIdx.x * 2 + 1] = b1;
    }
}

// Kernel 2: single block reduces nblocks partial pairs, writes final 2 floats.
__global__ __launch_bounds__(NTHREADS) void cl_final(
    const float* __restrict__ ws,
    float* __restrict__ out,
    int nblocks,
    float invN)
{
    double s0 = 0.0, s1 = 0.0;
    for (int j = threadIdx.x; j < nblocks; j += NTHREADS) {
        s0 += (double)ws[j * 2 + 0];
        s1 += (double)ws[j * 2 + 1];
    }

    #pragma unroll
    for (int off = 32; off > 0; off >>= 1) {
        s0 += __shfl_down(s0, off, 64);
        s1 += __shfl_down(s1, off, 64);
    }

    __shared__ double sm[ (NTHREADS/64) * 2 ];
    int wave = threadIdx.x >> 6;
    int lane = threadIdx.x & 63;
    if (lane == 0) { sm[wave * 2 + 0] = s0; sm[wave * 2 + 1] = s1; }
    __syncthreads();

    if (threadIdx.x == 0) {
        double b0 = 0.0, b1 = 0.0;
        #pragma unroll
        for (int wv = 0; wv < NTHREADS / 64; ++wv) {
            b0 += sm[wv * 2 + 0];
            b1 += sm[wv * 2 + 1];
        }
        out[0] = (float)(-b0 * (double)invN);
        out[1] = (float)(-b1 * (double)invN);
    }
}

extern "C" void kernel_launch(void* const* d_in, const int* in_sizes, int n_in,
                              void* d_out, int out_size, void* d_ws, size_t ws_size,
                              hipStream_t stream) {
    const float* outputs = (const float*)d_in[0];  // (B,T,2)
    const float* targets = (const float*)d_in[1];  // (B,T,2)
    const float* weights = (const float*)d_in[2];  // (B,T)

    int N = in_sizes[2];        // B*T
    int M = N / 2;              // float4 groups

    float* ws = (float*)d_ws;
    float* out = (float*)d_out;

    int nblocks = (M + NTHREADS - 1) / NTHREADS;
    if (nblocks > NBLOCKS) nblocks = NBLOCKS;

    cl_partial<<<nblocks, NTHREADS, 0, stream>>>(
        (const float4*)outputs, (const float4*)targets, (const float2*)weights,
        ws, M);

    cl_final<<<1, NTHREADS, 0, stream>>>(ws, out, nblocks, 1.0f / (float)N);
}